// Round 2
// baseline (711.417 us; speedup 1.0000x reference)
//
#include <hip/hip_runtime.h>

#define Hh 512
#define Ww 512
#define TH 64
#define TW 64
#define TR 84        // TH + 20 (vertical halo rows of t / x tile rows)
#define XS 88        // x tile row stride (mult of 4, 88 mod 32 = 24)
#define TS 132       // t row stride in floats (64 cols * 2 g + 4 pad; 132 mod 32 = 4)
#define NPAIR 24

// dedup: out channel o uses input channel o/22 and kernel o/3 -> only 24
// distinct (c,k) pairs: p=0..23, c=p>>3, k=p-c. Duplicates get fan-out writes.
// Separability: base kernels are outer(g1,g1); mixed kernel = sum of 4 rank-1
// terms. Factors recovered from center row: a[j] = W[10][j]/sqrt(W[10][10]).

__global__ __launch_bounds__(256, 2) void gcm_sep(
    const float* __restrict__ x,
    const float* __restrict__ wgt,
    const float* __restrict__ bw,
    float* __restrict__ out)
{
    __shared__ __align__(16) float sx[TR * XS];   // 29.6 KB
    __shared__ __align__(16) float st[TR * TS];   // 44.4 KB (2 g-planes interleaved)
    __shared__ float sa[4 * 21];                  // horizontal taps
    __shared__ float sv[4 * 21];                  // vertical taps (w-folded)

    const int tid = threadIdx.x;
    const int bx = blockIdx.x, by = blockIdx.y, bz = blockIdx.z;
    const int b = bz / NPAIR;
    const int p = bz - b * NPAIR;
    const int c = p >> 3;
    const int k = p - c;

    // ---- separable factors (once per block)
    if (tid < 84) {
        const int g = tid / 21, j = tid - g * 21;
        const float* Wk = bw + (size_t)(g * 22 + k) * 441;
        const float a = Wk[210 + j] / sqrtf(Wk[220]);  // row 10, col j / sqrt(center)
        sa[tid] = a;
        sv[tid] = a * wgt[(b * 4 + g) * 22 + k];
    }

    // ---- stage x tile (halo, zero-padded)
    const int gx0 = bx * TW - 10, gy0 = by * TH - 10;
    const float* xc = x + (size_t)(b * 3 + c) * (Hh * Ww);
    for (int idx = tid; idx < TR * TR; idx += 256) {
        const int r = idx / TR, cc = idx - r * TR;
        const int gy = gy0 + r, gx = gx0 + cc;
        float v = 0.f;
        if ((unsigned)gy < (unsigned)Hh && (unsigned)gx < (unsigned)Ww)
            v = xc[gy * Ww + gx];
        sx[r * XS + cc] = v;
    }

    float acc[8][2];
    #pragma unroll
    for (int i = 0; i < 8; ++i) { acc[i][0] = 0.f; acc[i][1] = 0.f; }

    const int tr = tid >> 5, tc = tid & 31;   // phase-3 mapping: 8 tile-rows x 32 col-pairs
    const int y0 = tr * 8;

    #pragma unroll 1
    for (int pass = 0; pass < 2; ++pass) {
        const int gb = pass * 2;
        __syncthreads();   // pass0: taps+x staged; pass1: everyone done reading st

        float ha0[21], ha1[21];
        #pragma unroll
        for (int j = 0; j < 21; ++j) { ha0[j] = sa[gb*21 + j]; ha1[j] = sa[gb*21 + 21 + j]; }

        // ---- P2: horizontal conv, 8-col chunks, both g of the pair from one x window
        for (int cid = tid; cid < TR * 8; cid += 256) {
            const int r = cid >> 3, ch = cid & 7;
            float xw[28];
            const float* sp = &sx[r * XS + ch * 8];
            #pragma unroll
            for (int q = 0; q < 7; ++q) {
                const float4 v = *(const float4*)(sp + 4 * q);
                xw[4*q] = v.x; xw[4*q+1] = v.y; xw[4*q+2] = v.z; xw[4*q+3] = v.w;
            }
            float tv[8][2];
            #pragma unroll
            for (int cc = 0; cc < 8; ++cc) { tv[cc][0] = 0.f; tv[cc][1] = 0.f; }
            #pragma unroll
            for (int j = 0; j < 21; ++j) {
                #pragma unroll
                for (int cc = 0; cc < 8; ++cc) {
                    tv[cc][0] = fmaf(ha0[j], xw[cc + j], tv[cc][0]);
                    tv[cc][1] = fmaf(ha1[j], xw[cc + j], tv[cc][1]);
                }
            }
            float* tp = &st[r * TS + ch * 16];
            #pragma unroll
            for (int m = 0; m < 4; ++m) {
                const int mm = (m + ch) & 3;   // rotate write order: spread banks
                *(float4*)(tp + 4 * mm) =
                    make_float4(tv[2*mm][0], tv[2*mm][1], tv[2*mm+1][0], tv[2*mm+1][1]);
            }
        }
        __syncthreads();

        float va0[21], va1[21];
        #pragma unroll
        for (int j = 0; j < 21; ++j) { va0[j] = sv[gb*21 + j]; va1[j] = sv[gb*21 + 21 + j]; }

        // ---- P3: vertical conv, sliding window, 1 b128/row gives 2 cols x 2 g
        const float* rp = &st[y0 * TS + tc * 4];
        #pragma unroll
        for (int ro = 0; ro < 28; ++ro) {
            const float4 t4 = *(const float4*)(rp + ro * TS);
            #pragma unroll
            for (int yy = 0; yy < 8; ++yy) {
                if (yy <= ro && ro - yy <= 20) {     // compile-time per unrolled iter
                    const int i = ro - yy;
                    acc[yy][0] += va0[i] * t4.x + va1[i] * t4.y;
                    acc[yy][1] += va0[i] * t4.z + va1[i] * t4.w;
                }
            }
        }
    }

    // ---- fan-out writes to duplicate output channels
    const int oS = (3*k > 22*c) ? 3*k : 22*c;
    const int t1 = 3*k + 2, t2 = 22*c + 21;
    const int oE = (t1 < t2) ? t1 : t2;
    const int gy = by * TH + y0;
    const int gx = bx * TW + tc * 2;
    for (int o = oS; o <= oE; ++o) {
        float* ob = out + ((size_t)(b * 66 + o) * Hh + gy) * Ww + gx;
        #pragma unroll
        for (int yy = 0; yy < 8; ++yy)
            *(float2*)(ob + yy * Ww) = make_float2(acc[yy][0], acc[yy][1]);
    }
}

extern "C" void kernel_launch(void* const* d_in, const int* in_sizes, int n_in,
                              void* d_out, int out_size, void* d_ws, size_t ws_size,
                              hipStream_t stream) {
    const float* x   = (const float*)d_in[0];
    const float* wgt = (const float*)d_in[1];
    const float* bw  = (const float*)d_in[2];
    float* out = (float*)d_out;
    dim3 grid(Ww / TW, Hh / TH, 8 * NPAIR);
    gcm_sep<<<grid, 256, 0, stream>>>(x, wgt, bw, out);
}

// Round 3
// 221.867 us; speedup vs baseline: 3.2065x; 3.2065x over previous
//
#include <hip/hip_runtime.h>

typedef __attribute__((ext_vector_type(8))) short bfrag;   // 8 bf16 = 4 VGPR
typedef __attribute__((ext_vector_type(4))) float ffrag;   // MFMA 16x16 acc

#define NPAIR 24

__device__ __forceinline__ unsigned short f2b(float f) {   // f32 -> bf16 RTNE
    unsigned u = __builtin_bit_cast(unsigned, f);
    return (unsigned short)((u + 0x7FFFu + ((u >> 16) & 1u)) >> 16);
}

// Separable mixed-Gaussian grouped conv via two banded-MFMA passes.
// Pair p=0..23: c=p>>3, k=p-c. Tap factor a_g[j] = W[g,k,10,j]/sqrt(W[g,k,10,10]).
// P2: t_g[r][c] = w_g * sum_j a_g[j] x[r][c+j]   (A = x rows, B = banded taps)
// P3: out[y][c] += sum_g sum_i a_g[i] t_g[y+i][c] (A = banded taps, B = t cols)
// Band fragments depend only on d = 2*step - group  in {-1,0,1,2}  -> 8KB table.
__global__ __launch_bounds__(256, 3) void gcm_mfma(
    const float* __restrict__ x,
    const float* __restrict__ wgt,
    const float* __restrict__ bw,
    float* __restrict__ out)
{
    __shared__ __align__(16) short sx[96 * 104];      // x tile, bf16, stride 104
    __shared__ __align__(16) short st[64 * 104];      // t transposed [col][row]
    __shared__ __align__(16) short tab[4 * 4 * 64 * 8]; // [g][d+1][lane][8]
    __shared__ float tapF[4 * 96];                    // padded taps, f32

    const int tid  = threadIdx.x;
    const int lane = tid & 63;
    const int wv   = tid >> 6;        // wave id == column-group cg
    const int ln   = lane & 15;
    const int lq   = lane >> 4;

    // XCD-aware bijective swizzle: each XCD gets a contiguous logical chunk
    const int phys = blockIdx.x;
    const int logical = (phys & 7) * 1536 + (phys >> 3);
    const int bz  = logical >> 6;
    const int rem = logical & 63;
    const int by = rem >> 3, bx = rem & 7;
    const int b = bz / NPAIR;
    const int p = bz - b * NPAIR;
    const int c = p >> 3;
    const int k = p - c;

    // ---- padded tap factors (f32), index u = idx-32 in [-32, 64)
    for (int i = tid; i < 4 * 96; i += 256) {
        const int g = i / 96, u = (i - g * 96) - 32;
        float v = 0.f;
        if ((unsigned)u < 21u) {
            const float* Wk = bw + (size_t)(g * 22 + k) * 441;
            v = Wk[210 + u] / sqrtf(Wk[220]);
        }
        tapF[i] = v;
    }

    // ---- stage x tile -> bf16 (all entries written: no NaN garbage)
    const int gx0 = bx * 64 - 10, gy0 = by * 64 - 10;
    const float* xc = x + (size_t)(b * 3 + c) * (512 * 512);
    for (int i = tid; i < 96 * 52; i += 256) {
        const int row = i / 52, cp = i - row * 52;
        const int gy = gy0 + row;
        const int gx = gx0 + 2 * cp;
        float v0 = 0.f, v1 = 0.f;
        if (row < 84 && (unsigned)gy < 512u) {
            if ((unsigned)gx < 512u)       v0 = xc[gy * 512 + gx];
            if ((unsigned)(gx + 1) < 512u) v1 = xc[gy * 512 + gx + 1];
        }
        ((unsigned*)sx)[i] = (unsigned)f2b(v0) | ((unsigned)f2b(v1) << 16);
    }
    __syncthreads();

    // ---- build band-fragment table: entry[(g,di,l)][j] = a_g[16(di-1)+8*(l>>4)+j-(l&15)]
    for (int e = tid; e < 4 * 4 * 64; e += 256) {
        const int g  = e >> 8;
        const int di = (e >> 6) & 3;
        const int l  = e & 63;
        const int base = 16 * (di - 1) + 8 * (l >> 4) - (l & 15) + 32;
        const float* tp = &tapF[g * 96];
        unsigned pk0 = (unsigned)f2b(tp[base + 0]) | ((unsigned)f2b(tp[base + 1]) << 16);
        unsigned pk1 = (unsigned)f2b(tp[base + 2]) | ((unsigned)f2b(tp[base + 3]) << 16);
        unsigned pk2 = (unsigned)f2b(tp[base + 4]) | ((unsigned)f2b(tp[base + 5]) << 16);
        unsigned pk3 = (unsigned)f2b(tp[base + 6]) | ((unsigned)f2b(tp[base + 7]) << 16);
        *(uint4*)&tab[e * 8] = make_uint4(pk0, pk1, pk2, pk3);
    }

    // ---- preload this wave's x fragments: rows 16rg+ln, k-steps {s0, s0+1}
    const int s0 = wv >> 1;
    bfrag xa[6][2];
    #pragma unroll
    for (int rg = 0; rg < 6; ++rg) {
        xa[rg][0] = *(const bfrag*)&sx[(16 * rg + ln) * 104 + 32 * s0 + 8 * lq];
        xa[rg][1] = *(const bfrag*)&sx[(16 * rg + ln) * 104 + 32 * (s0 + 1) + 8 * lq];
    }
    __syncthreads();   // tab ready; sx reads done before st aliasing? (st separate) -> P2 may start

    ffrag acc3[4];
    #pragma unroll
    for (int yg = 0; yg < 4; ++yg) acc3[yg] = ffrag{0.f, 0.f, 0.f, 0.f};

    #pragma unroll 1
    for (int g = 0; g < 4; ++g) {
        const float wg = wgt[(b * 4 + g) * 22 + k];
        // P2: horizontal conv -> t (transposed store), scaled by wg
        const bfrag tb0 = *(const bfrag*)&tab[((g * 4 + (2 * s0 - wv + 1)) * 64 + lane) * 8];
        const bfrag tb1 = *(const bfrag*)&tab[((g * 4 + (2 * s0 + 2 - wv + 1)) * 64 + lane) * 8];
        #pragma unroll
        for (int rg = 0; rg < 6; ++rg) {
            ffrag a = ffrag{0.f, 0.f, 0.f, 0.f};
            a = __builtin_amdgcn_mfma_f32_16x16x32_bf16(xa[rg][0], tb0, a, 0, 0, 0);
            a = __builtin_amdgcn_mfma_f32_16x16x32_bf16(xa[rg][1], tb1, a, 0, 0, 0);
            // lane holds rows r=16rg+4lq+{0..3}, col c=16wv+ln
            const unsigned lo = (unsigned)f2b(a.x * wg) | ((unsigned)f2b(a.y * wg) << 16);
            const unsigned hi = (unsigned)f2b(a.z * wg) | ((unsigned)f2b(a.w * wg) << 16);
            *(uint2*)&st[(16 * wv + ln) * 104 + 16 * rg + 4 * lq] = make_uint2(lo, hi);
        }
        __syncthreads();
        // P3: vertical conv, accumulate into acc3
        bfrag tbv[3];
        #pragma unroll
        for (int s = 0; s < 3; ++s)
            tbv[s] = *(const bfrag*)&st[(16 * wv + ln) * 104 + 32 * s + 8 * lq];
        #pragma unroll
        for (int yg = 0; yg < 4; ++yg) {
            const int sa = yg >> 1;
            #pragma unroll
            for (int si = 0; si < 2; ++si) {
                const int s  = sa + si;
                const int di = 2 * s - yg + 1;
                const bfrag ta = *(const bfrag*)&tab[((g * 4 + di) * 64 + lane) * 8];
                acc3[yg] = __builtin_amdgcn_mfma_f32_16x16x32_bf16(ta, tbv[s], acc3[yg], 0, 0, 0);
            }
        }
        __syncthreads();  // before next g overwrites st
    }

    // ---- fan-out stores: lane holds out[y=16yg+4lq+reg][c=16wv+ln]
    const int oS = (3 * k > 22 * c) ? 3 * k : 22 * c;
    const int t1 = 3 * k + 2, t2 = 22 * c + 21;
    const int oE = (t1 < t2) ? t1 : t2;
    const int gxo = bx * 64 + 16 * wv + ln;
    #pragma unroll
    for (int yg = 0; yg < 4; ++yg) {
        const int gy = by * 64 + 16 * yg + 4 * lq;
        for (int o = oS; o <= oE; ++o) {
            float* ob = out + ((size_t)(b * 66 + o) * 512 + gy) * 512 + gxo;
            ob[0]    = acc3[yg].x;
            ob[512]  = acc3[yg].y;
            ob[1024] = acc3[yg].z;
            ob[1536] = acc3[yg].w;
        }
    }
}

extern "C" void kernel_launch(void* const* d_in, const int* in_sizes, int n_in,
                              void* d_out, int out_size, void* d_ws, size_t ws_size,
                              hipStream_t stream) {
    const float* x   = (const float*)d_in[0];
    const float* wgt = (const float*)d_in[1];
    const float* bw  = (const float*)d_in[2];
    float* out = (float*)d_out;
    gcm_mfma<<<dim3(8 * 8 * 8 * NPAIR), 256, 0, stream>>>(x, wgt, bw, out);
}